// Round 8
// baseline (719.304 us; speedup 1.0000x reference)
//
#include <hip/hip_runtime.h>
#include <cstdint>

#define N_NODES 50000
#define IN_DIM 256
#define H_HEADS 8
#define D_HEAD 64
#define HD 512
#define OUT_DIM 64
#define M_PATHS 2
#define E_EDGES 800000
#define SEM_HID 128
#define NEG_SLOPE 0.2f
#define ELL_CAP 64
#define HN 3200000  // N_NODES * 64 (one head-slab of featb/z)

typedef __attribute__((ext_vector_type(8))) short bf16x8;
typedef __attribute__((ext_vector_type(4))) float f32x4;
typedef __attribute__((ext_vector_type(8))) unsigned short u16x8;

// ---- bf16 helpers ----
__device__ __forceinline__ float b2f(unsigned short u) {
  return __uint_as_float(((unsigned)u) << 16);
}
__device__ __forceinline__ unsigned short f2b(float f) {
  unsigned u = __float_as_uint(f);
  unsigned r = (u + 0x7fffu + ((u >> 16) & 1u)) >> 16;
  return (unsigned short)r;
}

__device__ __forceinline__ float eluf(float x) {
  return x > 0.f ? x : (expf(x) - 1.f);
}
__device__ __forceinline__ float lrelu(float x) {
  return x > 0.f ? x : NEG_SLOPE * x;
}

// ---- prep: weight transposes, WALR = Wg @ [al|ar], zero deg2/wsem ----
__global__ void k_prep(const float* __restrict__ Wg, const float* __restrict__ W1,
                       const float* __restrict__ Wout, const float* __restrict__ al,
                       const float* __restrict__ ar,
                       unsigned short* __restrict__ WgbT, unsigned short* __restrict__ W1T,
                       unsigned short* __restrict__ WoutT, unsigned short* __restrict__ WALR,
                       int* __restrict__ deg2, float* __restrict__ wsem) {
  int gid = blockIdx.x * blockDim.x + threadIdx.x;
  if (gid < 262144) {
    int m = gid >> 17, r = gid & 131071, n = r >> 8, k = r & 255;
    WgbT[(size_t)m * 131072 + n * 256 + k] = f2b(Wg[(size_t)m * 131072 + k * 512 + n]);
  } else if (gid < 327680) {
    int r = gid - 262144; int c = r >> 9, k = r & 511;
    W1T[c * 512 + k] = f2b(W1[k * 128 + c]);
  } else if (gid < 360448) {
    int r = gid - 327680; int c = r >> 9, k = r & 511;
    WoutT[c * 512 + k] = f2b(Wout[k * 64 + c]);
  } else if (gid < 368640) {
    int r = gid - 360448;          // 8192 = 32 cols x 256 k
    int c = r >> 8, k = r & 255;
    int m = c >> 4, side = (c >> 3) & 1, h = c & 7;
    const float* av = (side ? ar : al) + m * HD + h * D_HEAD;
    const float* wrow = Wg + (size_t)m * 131072 + (size_t)k * HD + h * D_HEAD;
    float s = 0.f;
#pragma unroll
    for (int d = 0; d < 64; ++d) s += wrow[d] * av[d];
    WALR[c * 256 + k] = f2b(s);
  } else if (gid < 468640) {
    deg2[gid - 368640] = 0;
  } else if (gid < 468642) {
    wsem[gid - 468640] = 0.f;
  }
}

// ---- elx: xb = bf16(x); [el|er][m][h][n] = x @ WALR^T (32 cols MFMA) ----
__global__ __launch_bounds__(256) void k_elx(const float* __restrict__ xfp,
                                             const unsigned short* __restrict__ WALR,
                                             unsigned short* __restrict__ xb,
                                             float* __restrict__ el2,
                                             float* __restrict__ er2) {
  __shared__ __align__(16) unsigned short As[64][72];
  __shared__ __align__(16) unsigned short Bs[32][72];
  const int tid = threadIdx.x;
  const int r0 = blockIdx.x * 64;
  const int w = tid >> 6, lane = tid & 63;
  const int cl = lane & 15, kg = lane >> 4;
  f32x4 acc[2] = {};
  for (int k0 = 0; k0 < IN_DIM; k0 += 64) {
#pragma unroll
    for (int p = 0; p < 2; ++p) {
      int idx = tid + p * 256;
      int row = idx >> 3, ko = (idx & 7) * 8;
      u16x8 v = (u16x8)(unsigned short)0;
      int grow = r0 + row;
      if (grow < N_NODES) {
        const float4* g = (const float4*)&xfp[(size_t)grow * IN_DIM + k0 + ko];
        float4 g0 = g[0], g1 = g[1];
        v[0] = f2b(g0.x); v[1] = f2b(g0.y); v[2] = f2b(g0.z); v[3] = f2b(g0.w);
        v[4] = f2b(g1.x); v[5] = f2b(g1.y); v[6] = f2b(g1.z); v[7] = f2b(g1.w);
        *(u16x8*)&xb[(size_t)grow * IN_DIM + k0 + ko] = v;
      }
      *(u16x8*)&As[row][ko] = v;
    }
    {
      int col = tid >> 3, ko = (tid & 7) * 8;
      *(u16x8*)&Bs[col][ko] = *(const u16x8*)&WALR[col * 256 + k0 + ko];
    }
    __syncthreads();
#pragma unroll
    for (int kk = 0; kk < 64; kk += 32) {
      bf16x8 a = *(const bf16x8*)&As[w * 16 + cl][kk + kg * 8];
#pragma unroll
      for (int ct = 0; ct < 2; ++ct) {
        bf16x8 b = *(const bf16x8*)&Bs[ct * 16 + cl][kk + kg * 8];
        acc[ct] = __builtin_amdgcn_mfma_f32_16x16x32_bf16(a, b, acc[ct], 0, 0, 0);
      }
    }
    __syncthreads();
  }
#pragma unroll
  for (int ct = 0; ct < 2; ++ct) {
    int col = ct * 16 + cl;
    int m = col >> 4, side = (col >> 3) & 1, h = col & 7;
    float* dstp = (side ? er2 : el2) + m * 400000 + h * N_NODES;
#pragma unroll
    for (int reg = 0; reg < 4; ++reg) {
      int row = r0 + w * 16 + kg * 4 + reg;
      if (row < N_NODES) dstp[row] = acc[ct][reg];
    }
  }
}

// ---- edge pass: build u16 ELL adjacency (by dst) ----
__global__ void k_edge_e(const int* __restrict__ src, const int* __restrict__ dst,
                         int* __restrict__ deg, unsigned short* __restrict__ ell_src) {
  int e = blockIdx.x * blockDim.x + threadIdx.x;
  if (e >= E_EDGES) return;
  int d = dst[e];
  int p = atomicAdd(&deg[d], 1);
  if (p < ELL_CAP) ell_src[d * ELL_CAP + p] = (unsigned short)src[e];
}

// ---- GEMM 1: featb[H][N][64](bf16) = xb[N,256](bf16) @ WgbT, head-major out ----
__global__ __launch_bounds__(256) void k_gemm_feat(const unsigned short* __restrict__ xb,
                                                   const unsigned short* __restrict__ BT,
                                                   unsigned short* __restrict__ C) {
  __shared__ __align__(16) unsigned short As[64][72];
  __shared__ __align__(16) unsigned short Bs[256][72];
  const int tid = threadIdx.x;
  const int r0 = blockIdx.x * 64, c0 = blockIdx.y * 256;
  const int w = tid >> 6, lane = tid & 63;
  const int cl = lane & 15, kg = lane >> 4;
  const int rw = (w >> 1) * 32;
  const int cw = (w & 1) * 128;
  f32x4 acc[2][8] = {};
  for (int k0 = 0; k0 < IN_DIM; k0 += 64) {
#pragma unroll
    for (int p = 0; p < 2; ++p) {
      int idx = tid + p * 256;
      int row = idx >> 3, ko = (idx & 7) * 8;
      u16x8 v = (u16x8)(unsigned short)0;
      int grow = r0 + row;
      if (grow < N_NODES) v = *(const u16x8*)&xb[(size_t)grow * IN_DIM + k0 + ko];
      *(u16x8*)&As[row][ko] = v;
    }
#pragma unroll
    for (int p = 0; p < 8; ++p) {
      int idx = tid + p * 256;
      int col = idx >> 3, ko = (idx & 7) * 8;
      *(u16x8*)&Bs[col][ko] = *(const u16x8*)&BT[(size_t)(c0 + col) * IN_DIM + k0 + ko];
    }
    __syncthreads();
#pragma unroll
    for (int kk = 0; kk < 64; kk += 32) {
      bf16x8 a0 = *(const bf16x8*)&As[rw + cl][kk + kg * 8];
      bf16x8 a1 = *(const bf16x8*)&As[rw + 16 + cl][kk + kg * 8];
#pragma unroll
      for (int ct = 0; ct < 8; ++ct) {
        bf16x8 b = *(const bf16x8*)&Bs[cw + ct * 16 + cl][kk + kg * 8];
        acc[0][ct] = __builtin_amdgcn_mfma_f32_16x16x32_bf16(a0, b, acc[0][ct], 0, 0, 0);
        acc[1][ct] = __builtin_amdgcn_mfma_f32_16x16x32_bf16(a1, b, acc[1][ct], 0, 0, 0);
      }
    }
    __syncthreads();
  }
  const int ccol = c0 + cw;
#pragma unroll
  for (int rt = 0; rt < 2; ++rt)
#pragma unroll
    for (int ct = 0; ct < 8; ++ct)
#pragma unroll
      for (int reg = 0; reg < 4; ++reg) {
        int row = r0 + rw + rt * 16 + kg * 4 + reg;
        int col = ccol + ct * 16 + cl;
        int h = col >> 6, d = col & 63;
        if (row < N_NODES)
          C[(size_t)h * HN + (size_t)row * 64 + d] = f2b(acc[rt][ct][reg]);
      }
}

// ---- gather/aggregate: one wave per (node, head); h = blockIdx&7 (XCD pin) ----
__global__ __launch_bounds__(256) void k_agg(const unsigned short* __restrict__ featb,
                                             const float* __restrict__ el,
                                             const float* __restrict__ er,
                                             const unsigned short* __restrict__ ell_src,
                                             const int* __restrict__ deg,
                                             const float* __restrict__ bg,
                                             unsigned short* __restrict__ z) {
  const int tid = threadIdx.x;
  const int widx = tid >> 6, lane = tid & 63;
  const int bid = blockIdx.x;
  const int h = bid & 7;                 // head == XCD affinity (bid%8)
  const int n = (bid >> 3) * 4 + widx;
  // phase A: lane = edge index; butterfly softmax, no LDS
  int dcnt = min(deg[n], ELL_CAP);
  int s_raw = (int)ell_src[n * ELL_CAP + lane];
  int s_reg = min(s_raw, N_NODES - 1);
  float sc = lrelu(el[(size_t)h * N_NODES + s_reg] + er[(size_t)h * N_NODES + n]);
  const bool valid = lane < dcnt;
  if (!valid) sc = -1e30f;
  float mxv = sc;
#pragma unroll
  for (int off = 1; off < 64; off <<= 1) mxv = fmaxf(mxv, __shfl_xor(mxv, off));
  float ex = valid ? expf(sc - mxv) : 0.f;
  float den = ex;
#pragma unroll
  for (int off = 1; off < 64; off <<= 1) den += __shfl_xor(den, off);
  const float ds = 1.f / fmaxf(den, 1e-9f);
  // phase B: 8 edges in flight (8 lanes/edge x 8 dims/lane)
  const int g = lane >> 3;        // edge slot
  const int dlo = (lane & 7) * 8; // dim base
  const unsigned short* fbh = featb + (size_t)h * HN + dlo;
  float acc[8] = {};
  int i = 0;
  for (; i + 16 <= dcnt; i += 16) {
    int e0 = i + g, e1 = i + 8 + g;
    float w0 = __shfl(ex, e0);
    float w1 = __shfl(ex, e1);
    int s0 = __shfl(s_reg, e0);
    int s1 = __shfl(s_reg, e1);
    u16x8 f0 = *(const u16x8*)&fbh[(size_t)s0 * 64];
    u16x8 f1 = *(const u16x8*)&fbh[(size_t)s1 * 64];
#pragma unroll
    for (int j = 0; j < 8; ++j) acc[j] += w0 * b2f(f0[j]);
#pragma unroll
    for (int j = 0; j < 8; ++j) acc[j] += w1 * b2f(f1[j]);
  }
  for (; i < dcnt; i += 8) {
    int e0 = i + g;                      // i <= 56, g <= 7 -> e0 <= 63
    float w0 = __shfl(ex, e0);           // ex == 0 for e0 >= dcnt
    int s0 = __shfl(s_reg, e0);
    u16x8 f0 = *(const u16x8*)&fbh[(size_t)s0 * 64];
#pragma unroll
    for (int j = 0; j < 8; ++j) acc[j] += w0 * b2f(f0[j]);
  }
  // reduce across the 8 edge-slot groups
#pragma unroll
  for (int off = 8; off < 64; off <<= 1)
#pragma unroll
    for (int j = 0; j < 8; ++j) acc[j] += __shfl_xor(acc[j], off);
  if (g == 0) {
    u16x8 zo;
#pragma unroll
    for (int j = 0; j < 8; ++j)
      zo[j] = f2b(eluf(acc[j] * ds + bg[h * 64 + dlo + j]));
    *(u16x8*)&z[(size_t)h * HN + (size_t)n * 64 + dlo] = zo;
  }
}

// ---- GEMM 2 (fused): [hidden|y] = z @ [W1|Wout]; 128 rows/block ----
__global__ __launch_bounds__(256) void k_gemm_post(const unsigned short* __restrict__ Zb,
                                                   const unsigned short* __restrict__ W1T,
                                                   const unsigned short* __restrict__ WoutT,
                                                   const float* __restrict__ b1,
                                                   const float* __restrict__ qv,
                                                   float* __restrict__ wsem_m,
                                                   unsigned short* __restrict__ yb) {
  __shared__ __align__(16) unsigned short As[128][72];
  __shared__ __align__(16) unsigned short Bs[192][72];
  __shared__ float redv[16];
  const int tid = threadIdx.x;
  const int r0 = blockIdx.x * 128;
  const int w = tid >> 6, lane = tid & 63;
  const int cl = lane & 15, kg = lane >> 4;
  const int rw = w * 32;
  f32x4 acc[2][12] = {};
  for (int k0 = 0; k0 < HD; k0 += 64) {
#pragma unroll
    for (int p = 0; p < 4; ++p) {
      int idx = tid + p * 256;
      int row = idx >> 3, ko = (idx & 7) * 8;
      int kc = k0 + ko, hh = kc >> 6, dd = kc & 63;
      u16x8 v = (u16x8)(unsigned short)0;
      if (r0 + row < N_NODES)
        v = *(const u16x8*)&Zb[(size_t)hh * HN + (size_t)(r0 + row) * 64 + dd];
      *(u16x8*)&As[row][ko] = v;
    }
#pragma unroll
    for (int p = 0; p < 6; ++p) {
      int idx = tid + p * 256;
      int col = idx >> 3, ko = (idx & 7) * 8;
      u16x8 v = (col < 128) ? *(const u16x8*)&W1T[(size_t)col * HD + k0 + ko]
                            : *(const u16x8*)&WoutT[(size_t)(col - 128) * HD + k0 + ko];
      *(u16x8*)&Bs[col][ko] = v;
    }
    __syncthreads();
#pragma unroll
    for (int kk = 0; kk < 64; kk += 32) {
      bf16x8 a0 = *(const bf16x8*)&As[rw + cl][kk + kg * 8];
      bf16x8 a1 = *(const bf16x8*)&As[rw + 16 + cl][kk + kg * 8];
#pragma unroll
      for (int ct = 0; ct < 12; ++ct) {
        bf16x8 b = *(const bf16x8*)&Bs[ct * 16 + cl][kk + kg * 8];
        acc[0][ct] = __builtin_amdgcn_mfma_f32_16x16x32_bf16(a0, b, acc[0][ct], 0, 0, 0);
        acc[1][ct] = __builtin_amdgcn_mfma_f32_16x16x32_bf16(a1, b, acc[1][ct], 0, 0, 0);
      }
    }
    __syncthreads();
  }
  float rs[2][4] = {};
#pragma unroll
  for (int ct = 0; ct < 8; ++ct) {
    int col = ct * 16 + cl;
    float bb = b1[col], qq = qv[col];
#pragma unroll
    for (int rt = 0; rt < 2; ++rt)
#pragma unroll
      for (int reg = 0; reg < 4; ++reg)
        rs[rt][reg] += tanhf(acc[rt][ct][reg] + bb) * qq;
  }
#pragma unroll
  for (int off = 1; off < 16; off <<= 1)
#pragma unroll
    for (int rt = 0; rt < 2; ++rt)
#pragma unroll
      for (int reg = 0; reg < 4; ++reg) rs[rt][reg] += __shfl_xor(rs[rt][reg], off);
  float val = 0.f;
#pragma unroll
  for (int rt = 0; rt < 2; ++rt)
#pragma unroll
    for (int reg = 0; reg < 4; ++reg) {
      int row = r0 + rw + rt * 16 + kg * 4 + reg;
      if (row < N_NODES) val += rs[rt][reg];
    }
  if (cl == 0) redv[w * 4 + kg] = val;
  __syncthreads();
  if (tid == 0) {
    float sv = 0.f;
#pragma unroll
    for (int k = 0; k < 16; ++k) sv += redv[k];
    atomicAdd(wsem_m, sv);
  }
#pragma unroll
  for (int rt = 0; rt < 2; ++rt)
#pragma unroll
    for (int ct = 8; ct < 12; ++ct)
#pragma unroll
      for (int reg = 0; reg < 4; ++reg) {
        int row = r0 + rw + rt * 16 + kg * 4 + reg;
        if (row < N_NODES)
          yb[(size_t)row * OUT_DIM + (ct - 8) * 16 + cl] = f2b(acc[rt][ct][reg]);
      }
}

// ---- final: beta inline from wsem; out = beta0*y0 + beta1*y1 + bout ----
__global__ void k_final(const unsigned short* __restrict__ yb, const float* __restrict__ wsem,
                        const float* __restrict__ bout, float* __restrict__ out) {
  int gid = blockIdx.x * blockDim.x + threadIdx.x;
  size_t off = (size_t)gid * 8;
  if (off >= (size_t)N_NODES * OUT_DIM) return;
  float w0 = wsem[0] / (float)N_NODES, w1 = wsem[1] / (float)N_NODES;
  float mxv = fmaxf(w0, w1);
  float e0 = expf(w0 - mxv), e1 = expf(w1 - mxv);
  float inv = 1.f / (e0 + e1);
  float b0 = e0 * inv, b1v = e1 * inv;
  u16x8 ya = *(const u16x8*)&yb[off];
  u16x8 yc = *(const u16x8*)&yb[(size_t)N_NODES * OUT_DIM + off];
  const int cb = (int)(off & 63);
#pragma unroll
  for (int j = 0; j < 8; ++j)
    out[off + j] = b0 * b2f(ya[j]) + b1v * b2f(yc[j]) + bout[cb + j];
}

extern "C" void kernel_launch(void* const* d_in, const int* in_sizes, int n_in,
                              void* d_out, int out_size, void* d_ws, size_t ws_size,
                              hipStream_t stream) {
  const float* x    = (const float*)d_in[0];
  const int*   src  = (const int*)d_in[1];
  const int*   dst  = (const int*)d_in[2];
  const float* Wg   = (const float*)d_in[3];
  const float* al   = (const float*)d_in[4];
  const float* ar   = (const float*)d_in[5];
  const float* bg   = (const float*)d_in[6];
  const float* W1   = (const float*)d_in[7];
  const float* b1   = (const float*)d_in[8];
  const float* q    = (const float*)d_in[9];
  const float* Wout = (const float*)d_in[10];
  const float* bout = (const float*)d_in[11];
  float* out = (float*)d_out;

  // workspace layout (bytes, 64B aligned); total ~154.7 MB
  char* ws = (char*)d_ws;
  unsigned short* featb = (unsigned short*)(ws);                 // 51,200,000 [H][N][64]
  unsigned short* z     = (unsigned short*)(ws + 51200000);      // 51,200,000 [H][N][64]
  unsigned short* yb    = (unsigned short*)(ws + 102400000);     // 12,800,000
  unsigned short* xb    = (unsigned short*)(ws + 115200000);     // 25,600,000
  unsigned short* ell   = (unsigned short*)(ws + 140800000);     //  6,400,000 (u16, per-m reuse)
  float* el2            = (float*)(ws + 147200000);              //  3,200,000 [M][H][N]
  float* er2            = (float*)(ws + 150400000);              //  3,200,000 [M][H][N]
  int* deg2             = (int*)(ws + 153600000);                //    400,000 [2][N]
  unsigned short* WgbT  = (unsigned short*)(ws + 154000000);     //    524,288
  unsigned short* W1T   = (unsigned short*)(ws + 154524288);     //    131,072
  unsigned short* WoutT = (unsigned short*)(ws + 154655360);     //     65,536
  unsigned short* WALR  = (unsigned short*)(ws + 154720896);     //     16,384
  float* wsem           = (float*)(ws + 154737280);              //         64

  k_prep<<<1831, 256, 0, stream>>>(Wg, W1, Wout, al, ar, WgbT, W1T, WoutT, WALR,
                                   deg2, wsem);
  k_elx<<<782, 256, 0, stream>>>(x, WALR, xb, el2, er2);

  for (int m = 0; m < M_PATHS; ++m) {
    const int* srcm = src + (size_t)m * E_EDGES;
    const int* dstm = dst + (size_t)m * E_EDGES;
    k_edge_e<<<3125, 256, 0, stream>>>(srcm, dstm, deg2 + m * N_NODES, ell);
    dim3 gf(782, 2);
    k_gemm_feat<<<gf, 256, 0, stream>>>(xb, WgbT + (size_t)m * 131072, featb);
    k_agg<<<100000, 256, 0, stream>>>(featb, el2 + m * 400000, er2 + m * 400000,
                                      ell, deg2 + m * N_NODES, bg + m * HD, z);
    k_gemm_post<<<391, 256, 0, stream>>>(z, W1T, WoutT, b1, q, wsem + m,
                                         yb + (size_t)m * N_NODES * OUT_DIM);
  }
  k_final<<<1563, 256, 0, stream>>>(yb, wsem, bout, out);
}

// Round 10
// 537.198 us; speedup vs baseline: 1.3390x; 1.3390x over previous
//
#include <hip/hip_runtime.h>
#include <cstdint>

#define N_NODES 50000
#define IN_DIM 256
#define H_HEADS 8
#define D_HEAD 64
#define HD 512
#define OUT_DIM 64
#define M_PATHS 2
#define E_EDGES 800000
#define SEM_HID 128
#define NEG_SLOPE 0.2f
#define ELL_CAP 64
#define ELX_BLOCKS 782

typedef __attribute__((ext_vector_type(8))) short bf16x8;
typedef __attribute__((ext_vector_type(4))) float f32x4;
typedef __attribute__((ext_vector_type(8))) unsigned short u16x8;

// ---- bf16 helpers ----
__device__ __forceinline__ float b2f(unsigned short u) {
  return __uint_as_float(((unsigned)u) << 16);
}
__device__ __forceinline__ unsigned short f2b(float f) {
  unsigned u = __float_as_uint(f);
  unsigned r = (u + 0x7fffu + ((u >> 16) & 1u)) >> 16;
  return (unsigned short)r;
}

__device__ __forceinline__ float eluf(float x) {
  return x > 0.f ? x : (expf(x) - 1.f);
}
__device__ __forceinline__ float lrelu(float x) {
  return x > 0.f ? x : NEG_SLOPE * x;
}

// ---- prep: weight transposes, WALR = Wg @ [al|ar], zero deg2/wsem ----
__global__ void k_prep(const float* __restrict__ Wg, const float* __restrict__ W1,
                       const float* __restrict__ Wout, const float* __restrict__ al,
                       const float* __restrict__ ar,
                       unsigned short* __restrict__ WgbT, unsigned short* __restrict__ W1T,
                       unsigned short* __restrict__ WoutT, unsigned short* __restrict__ WALR,
                       int* __restrict__ deg2, float* __restrict__ wsem) {
  int gid = blockIdx.x * blockDim.x + threadIdx.x;
  if (gid < 262144) {
    int m = gid >> 17, r = gid & 131071, n = r >> 8, k = r & 255;
    WgbT[(size_t)m * 131072 + n * 256 + k] = f2b(Wg[(size_t)m * 131072 + k * 512 + n]);
  } else if (gid < 327680) {
    int r = gid - 262144; int c = r >> 9, k = r & 511;
    W1T[c * 512 + k] = f2b(W1[k * 128 + c]);
  } else if (gid < 360448) {
    int r = gid - 327680; int c = r >> 9, k = r & 511;
    WoutT[c * 512 + k] = f2b(Wout[k * 64 + c]);
  } else if (gid < 368640) {
    int r = gid - 360448;          // 8192 = 32 cols x 256 k
    int c = r >> 8, k = r & 255;
    int m = c >> 4, side = (c >> 3) & 1, h = c & 7;
    const float* av = (side ? ar : al) + m * HD + h * D_HEAD;
    const float* wrow = Wg + (size_t)m * 131072 + (size_t)k * HD + h * D_HEAD;
    float s = 0.f;
#pragma unroll
    for (int d = 0; d < 64; ++d) s += wrow[d] * av[d];
    WALR[c * 256 + k] = f2b(s);
  } else if (gid < 468640) {
    deg2[gid - 368640] = 0;
  } else if (gid < 468642) {
    wsem[gid - 468640] = 0.f;
  }
}

// ---- fused: [blocks 0..781] elx (xb=bf16(x), el/er via 32-col MFMA)
//             [blocks 782..3906] edge pass for m=0 (ELL build) ----
__global__ __launch_bounds__(256) void k_elx_edge(const float* __restrict__ xfp,
                                                  const unsigned short* __restrict__ WALR,
                                                  unsigned short* __restrict__ xb,
                                                  float* __restrict__ el2,
                                                  float* __restrict__ er2,
                                                  const int* __restrict__ src0,
                                                  const int* __restrict__ dst0,
                                                  int* __restrict__ deg0,
                                                  unsigned short* __restrict__ ell) {
  __shared__ __align__(16) unsigned short As[64][72];
  __shared__ __align__(16) unsigned short Bs[32][72];
  const int tid = threadIdx.x;
  if (blockIdx.x >= ELX_BLOCKS) {
    int e = (blockIdx.x - ELX_BLOCKS) * 256 + tid;
    if (e < E_EDGES) {
      int d = dst0[e];
      int p = atomicAdd(&deg0[d], 1);
      if (p < ELL_CAP) ell[d * ELL_CAP + p] = (unsigned short)src0[e];
    }
    return;
  }
  const int r0 = blockIdx.x * 64;
  const int w = tid >> 6, lane = tid & 63;
  const int cl = lane & 15, kg = lane >> 4;
  f32x4 acc[2] = {};
  for (int k0 = 0; k0 < IN_DIM; k0 += 64) {
#pragma unroll
    for (int p = 0; p < 2; ++p) {
      int idx = tid + p * 256;
      int row = idx >> 3, ko = (idx & 7) * 8;
      u16x8 v = (u16x8)(unsigned short)0;
      int grow = r0 + row;
      if (grow < N_NODES) {
        const float4* g = (const float4*)&xfp[(size_t)grow * IN_DIM + k0 + ko];
        float4 g0 = g[0], g1 = g[1];
        v[0] = f2b(g0.x); v[1] = f2b(g0.y); v[2] = f2b(g0.z); v[3] = f2b(g0.w);
        v[4] = f2b(g1.x); v[5] = f2b(g1.y); v[6] = f2b(g1.z); v[7] = f2b(g1.w);
        *(u16x8*)&xb[(size_t)grow * IN_DIM + k0 + ko] = v;
      }
      *(u16x8*)&As[row][ko] = v;
    }
    {
      int col = tid >> 3, ko = (tid & 7) * 8;
      *(u16x8*)&Bs[col][ko] = *(const u16x8*)&WALR[col * 256 + k0 + ko];
    }
    __syncthreads();
#pragma unroll
    for (int kk = 0; kk < 64; kk += 32) {
      bf16x8 a = *(const bf16x8*)&As[w * 16 + cl][kk + kg * 8];
#pragma unroll
      for (int ct = 0; ct < 2; ++ct) {
        bf16x8 b = *(const bf16x8*)&Bs[ct * 16 + cl][kk + kg * 8];
        acc[ct] = __builtin_amdgcn_mfma_f32_16x16x32_bf16(a, b, acc[ct], 0, 0, 0);
      }
    }
    __syncthreads();
  }
#pragma unroll
  for (int ct = 0; ct < 2; ++ct) {
    int col = ct * 16 + cl;
    int m = col >> 4, side = (col >> 3) & 1, h = col & 7;
    float* dstp = (side ? er2 : el2) + m * 400000;
#pragma unroll
    for (int reg = 0; reg < 4; ++reg) {
      int row = r0 + w * 16 + kg * 4 + reg;
      if (row < N_NODES) dstp[row * 8 + h] = acc[ct][reg];
    }
  }
}

// ---- edge pass (m=1): build u16 ELL adjacency (by dst) ----
__global__ void k_edge_e(const int* __restrict__ src, const int* __restrict__ dst,
                         int* __restrict__ deg, unsigned short* __restrict__ ell_src) {
  int e = blockIdx.x * blockDim.x + threadIdx.x;
  if (e >= E_EDGES) return;
  int d = dst[e];
  int p = atomicAdd(&deg[d], 1);
  if (p < ELL_CAP) ell_src[d * ELL_CAP + p] = (unsigned short)src[e];
}

// ---- GEMM 1: featb[N,512](bf16) = xb[N,256](bf16) @ WgbT ----
__global__ __launch_bounds__(256) void k_gemm_feat(const unsigned short* __restrict__ xb,
                                                   const unsigned short* __restrict__ BT,
                                                   unsigned short* __restrict__ C) {
  __shared__ __align__(16) unsigned short As[64][72];
  __shared__ __align__(16) unsigned short Bs[256][72];
  const int tid = threadIdx.x;
  const int r0 = blockIdx.x * 64, c0 = blockIdx.y * 256;
  const int w = tid >> 6, lane = tid & 63;
  const int cl = lane & 15, kg = lane >> 4;
  const int rw = (w >> 1) * 32;
  const int cw = (w & 1) * 128;
  f32x4 acc[2][8] = {};
  for (int k0 = 0; k0 < IN_DIM; k0 += 64) {
#pragma unroll
    for (int p = 0; p < 2; ++p) {
      int idx = tid + p * 256;
      int row = idx >> 3, ko = (idx & 7) * 8;
      u16x8 v = (u16x8)(unsigned short)0;
      int grow = r0 + row;
      if (grow < N_NODES) v = *(const u16x8*)&xb[(size_t)grow * IN_DIM + k0 + ko];
      *(u16x8*)&As[row][ko] = v;
    }
#pragma unroll
    for (int p = 0; p < 8; ++p) {
      int idx = tid + p * 256;
      int col = idx >> 3, ko = (idx & 7) * 8;
      *(u16x8*)&Bs[col][ko] = *(const u16x8*)&BT[(size_t)(c0 + col) * IN_DIM + k0 + ko];
    }
    __syncthreads();
#pragma unroll
    for (int kk = 0; kk < 64; kk += 32) {
      bf16x8 a0 = *(const bf16x8*)&As[rw + cl][kk + kg * 8];
      bf16x8 a1 = *(const bf16x8*)&As[rw + 16 + cl][kk + kg * 8];
#pragma unroll
      for (int ct = 0; ct < 8; ++ct) {
        bf16x8 b = *(const bf16x8*)&Bs[cw + ct * 16 + cl][kk + kg * 8];
        acc[0][ct] = __builtin_amdgcn_mfma_f32_16x16x32_bf16(a0, b, acc[0][ct], 0, 0, 0);
        acc[1][ct] = __builtin_amdgcn_mfma_f32_16x16x32_bf16(a1, b, acc[1][ct], 0, 0, 0);
      }
    }
    __syncthreads();
  }
  const int ccol = c0 + cw;
#pragma unroll
  for (int rt = 0; rt < 2; ++rt)
#pragma unroll
    for (int ct = 0; ct < 8; ++ct)
#pragma unroll
      for (int reg = 0; reg < 4; ++reg) {
        int row = r0 + rw + rt * 16 + kg * 4 + reg;
        if (row < N_NODES) C[(size_t)row * HD + ccol + ct * 16 + cl] = f2b(acc[rt][ct][reg]);
      }
}

// ---- gather/aggregate: one wave per node (R7-proven) ----
__global__ __launch_bounds__(256) void k_agg(const unsigned short* __restrict__ featb,
                                             const float* __restrict__ el,
                                             const float* __restrict__ er,
                                             const unsigned short* __restrict__ ell_src,
                                             const int* __restrict__ deg,
                                             const float* __restrict__ bg,
                                             unsigned short* __restrict__ z) {
  __shared__ float lds_ex[4][544];
  const int tid = threadIdx.x;
  const int widx = tid >> 6, lane = tid & 63;
  const int n = blockIdx.x * 4 + widx;
  const int h = lane >> 3;
  // phase A: single-level dependency — ell load unconditional
  int s_raw = (int)ell_src[n * ELL_CAP + lane];
  int dcnt_raw = deg[n];
  const float4* r4 = (const float4*)&er[n * 8];
  float4 b0 = r4[0], b1v = r4[1];
  int s_reg = s_raw;
  const float4* e4 = (const float4*)&el[s_reg * 8];
  float4 a0 = e4[0], a1 = e4[1];
  const int dcnt = min(dcnt_raw, ELL_CAP);
  const bool valid = lane < dcnt;
  float evf[8];
  evf[0] = lrelu(a0.x + b0.x); evf[1] = lrelu(a0.y + b0.y);
  evf[2] = lrelu(a0.z + b0.z); evf[3] = lrelu(a0.w + b0.w);
  evf[4] = lrelu(a1.x + b1v.x); evf[5] = lrelu(a1.y + b1v.y);
  evf[6] = lrelu(a1.z + b1v.z); evf[7] = lrelu(a1.w + b1v.w);
  if (!valid) {
#pragma unroll
    for (int j = 0; j < 8; ++j) evf[j] = -1e30f;
  }
  float mx[8];
#pragma unroll
  for (int j = 0; j < 8; ++j) mx[j] = evf[j];
#pragma unroll
  for (int off = 1; off < 64; off <<= 1)
#pragma unroll
    for (int j = 0; j < 8; ++j) mx[j] = fmaxf(mx[j], __shfl_xor(mx[j], off));
#pragma unroll
  for (int j = 0; j < 8; ++j) {
    float exv = valid ? expf(evf[j] - mx[j]) : 0.f;
    lds_ex[widx][j * 68 + lane] = exv;
  }
  // phase B: weighted aggregate, 8 rows in flight (plain cached loads)
  float acc[8] = {};
  float densum = 0.f;
  const float* exrow = &lds_ex[widx][h * 68];
  const unsigned short* fb = featb + lane * 8;
  int i = 0;
  for (; i + 8 <= dcnt; i += 8) {
    int ss[8];
    float ww[8];
    u16x8 ff[8];
#pragma unroll
    for (int u = 0; u < 8; ++u) {
      ss[u] = __shfl(s_reg, i + u);
      ww[u] = exrow[i + u];
    }
#pragma unroll
    for (int u = 0; u < 8; ++u) ff[u] = *(const u16x8*)&fb[(size_t)ss[u] * HD];
#pragma unroll
    for (int u = 0; u < 8; ++u) {
      densum += ww[u];
#pragma unroll
      for (int j = 0; j < 8; ++j) acc[j] += ww[u] * b2f(ff[u][j]);
    }
  }
  for (; i + 4 <= dcnt; i += 4) {
    int ss[4];
    float ww[4];
    u16x8 ff[4];
#pragma unroll
    for (int u = 0; u < 4; ++u) {
      ss[u] = __shfl(s_reg, i + u);
      ww[u] = exrow[i + u];
    }
#pragma unroll
    for (int u = 0; u < 4; ++u) ff[u] = *(const u16x8*)&fb[(size_t)ss[u] * HD];
#pragma unroll
    for (int u = 0; u < 4; ++u) {
      densum += ww[u];
#pragma unroll
      for (int j = 0; j < 8; ++j) acc[j] += ww[u] * b2f(ff[u][j]);
    }
  }
  for (; i < dcnt; ++i) {
    int s0 = __shfl(s_reg, i);
    float w0 = exrow[i];
    u16x8 f0 = *(const u16x8*)&fb[(size_t)s0 * HD];
    densum += w0;
#pragma unroll
    for (int j = 0; j < 8; ++j) acc[j] += w0 * b2f(f0[j]);
  }
  float ds = 1.f / fmaxf(densum, 1e-9f);
  const float4* bg4 = (const float4*)&bg[lane * 8];
  float4 bga = bg4[0], bgb = bg4[1];
  float bgv[8] = {bga.x, bga.y, bga.z, bga.w, bgb.x, bgb.y, bgb.z, bgb.w};
  u16x8 zo;
#pragma unroll
  for (int j = 0; j < 8; ++j) zo[j] = f2b(eluf(acc[j] * ds + bgv[j]));
  *(u16x8*)&z[(size_t)n * HD + lane * 8] = zo;
}

// ---- GEMM 2 (fused): [hidden|y] = z @ [W1|Wout]; 128 rows/block ----
__global__ __launch_bounds__(256) void k_gemm_post(const unsigned short* __restrict__ Zb,
                                                   const unsigned short* __restrict__ W1T,
                                                   const unsigned short* __restrict__ WoutT,
                                                   const float* __restrict__ b1,
                                                   const float* __restrict__ qv,
                                                   float* __restrict__ wsem_m,
                                                   unsigned short* __restrict__ yb) {
  __shared__ __align__(16) unsigned short As[128][72];
  __shared__ __align__(16) unsigned short Bs[192][72];
  __shared__ float redv[16];
  const int tid = threadIdx.x;
  const int r0 = blockIdx.x * 128;
  const int w = tid >> 6, lane = tid & 63;
  const int cl = lane & 15, kg = lane >> 4;
  const int rw = w * 32;
  f32x4 acc[2][12] = {};
  for (int k0 = 0; k0 < HD; k0 += 64) {
#pragma unroll
    for (int p = 0; p < 4; ++p) {
      int idx = tid + p * 256;
      int row = idx >> 3, ko = (idx & 7) * 8;
      u16x8 v = (u16x8)(unsigned short)0;
      if (r0 + row < N_NODES) v = *(const u16x8*)&Zb[(size_t)(r0 + row) * HD + k0 + ko];
      *(u16x8*)&As[row][ko] = v;
    }
#pragma unroll
    for (int p = 0; p < 6; ++p) {
      int idx = tid + p * 256;
      int col = idx >> 3, ko = (idx & 7) * 8;
      u16x8 v = (col < 128) ? *(const u16x8*)&W1T[(size_t)col * HD + k0 + ko]
                            : *(const u16x8*)&WoutT[(size_t)(col - 128) * HD + k0 + ko];
      *(u16x8*)&Bs[col][ko] = v;
    }
    __syncthreads();
#pragma unroll
    for (int kk = 0; kk < 64; kk += 32) {
      bf16x8 a0 = *(const bf16x8*)&As[rw + cl][kk + kg * 8];
      bf16x8 a1 = *(const bf16x8*)&As[rw + 16 + cl][kk + kg * 8];
#pragma unroll
      for (int ct = 0; ct < 12; ++ct) {
        bf16x8 b = *(const bf16x8*)&Bs[ct * 16 + cl][kk + kg * 8];
        acc[0][ct] = __builtin_amdgcn_mfma_f32_16x16x32_bf16(a0, b, acc[0][ct], 0, 0, 0);
        acc[1][ct] = __builtin_amdgcn_mfma_f32_16x16x32_bf16(a1, b, acc[1][ct], 0, 0, 0);
      }
    }
    __syncthreads();
  }
  float rs[2][4] = {};
#pragma unroll
  for (int ct = 0; ct < 8; ++ct) {
    int col = ct * 16 + cl;
    float bb = b1[col], qq = qv[col];
#pragma unroll
    for (int rt = 0; rt < 2; ++rt)
#pragma unroll
      for (int reg = 0; reg < 4; ++reg)
        rs[rt][reg] += tanhf(acc[rt][ct][reg] + bb) * qq;
  }
#pragma unroll
  for (int off = 1; off < 16; off <<= 1)
#pragma unroll
    for (int rt = 0; rt < 2; ++rt)
#pragma unroll
      for (int reg = 0; reg < 4; ++reg) rs[rt][reg] += __shfl_xor(rs[rt][reg], off);
  float val = 0.f;
#pragma unroll
  for (int rt = 0; rt < 2; ++rt)
#pragma unroll
    for (int reg = 0; reg < 4; ++reg) {
      int row = r0 + rw + rt * 16 + kg * 4 + reg;
      if (row < N_NODES) val += rs[rt][reg];
    }
  if (cl == 0) redv[w * 4 + kg] = val;
  __syncthreads();
  if (tid == 0) {
    float sv = 0.f;
#pragma unroll
    for (int k = 0; k < 16; ++k) sv += redv[k];
    atomicAdd(wsem_m, sv);
  }
#pragma unroll
  for (int rt = 0; rt < 2; ++rt)
#pragma unroll
    for (int ct = 8; ct < 12; ++ct)
#pragma unroll
      for (int reg = 0; reg < 4; ++reg) {
        int row = r0 + rw + rt * 16 + kg * 4 + reg;
        if (row < N_NODES)
          yb[(size_t)row * OUT_DIM + (ct - 8) * 16 + cl] = f2b(acc[rt][ct][reg]);
      }
}

// ---- final: beta inline from wsem; out = beta0*y0 + beta1*y1 + bout ----
__global__ void k_final(const unsigned short* __restrict__ yb, const float* __restrict__ wsem,
                        const float* __restrict__ bout, float* __restrict__ out) {
  int gid = blockIdx.x * blockDim.x + threadIdx.x;
  size_t off = (size_t)gid * 8;
  if (off >= (size_t)N_NODES * OUT_DIM) return;
  float w0 = wsem[0] / (float)N_NODES, w1 = wsem[1] / (float)N_NODES;
  float mxv = fmaxf(w0, w1);
  float e0 = expf(w0 - mxv), e1 = expf(w1 - mxv);
  float inv = 1.f / (e0 + e1);
  float b0 = e0 * inv, b1v = e1 * inv;
  u16x8 ya = *(const u16x8*)&yb[off];
  u16x8 yc = *(const u16x8*)&yb[(size_t)N_NODES * OUT_DIM + off];
  const int cb = (int)(off & 63);
#pragma unroll
  for (int j = 0; j < 8; ++j)
    out[off + j] = b0 * b2f(ya[j]) + b1v * b2f(yc[j]) + bout[cb + j];
}

extern "C" void kernel_launch(void* const* d_in, const int* in_sizes, int n_in,
                              void* d_out, int out_size, void* d_ws, size_t ws_size,
                              hipStream_t stream) {
  const float* x    = (const float*)d_in[0];
  const int*   src  = (const int*)d_in[1];
  const int*   dst  = (const int*)d_in[2];
  const float* Wg   = (const float*)d_in[3];
  const float* al   = (const float*)d_in[4];
  const float* ar   = (const float*)d_in[5];
  const float* bg   = (const float*)d_in[6];
  const float* W1   = (const float*)d_in[7];
  const float* b1   = (const float*)d_in[8];
  const float* q    = (const float*)d_in[9];
  const float* Wout = (const float*)d_in[10];
  const float* bout = (const float*)d_in[11];
  float* out = (float*)d_out;

  // workspace layout (bytes, 64B aligned); total ~154.7 MB (R7-proven)
  char* ws = (char*)d_ws;
  unsigned short* featb = (unsigned short*)(ws);                 // 51,200,000
  unsigned short* z     = (unsigned short*)(ws + 51200000);      // 51,200,000
  unsigned short* yb    = (unsigned short*)(ws + 102400000);     // 12,800,000
  unsigned short* xb    = (unsigned short*)(ws + 115200000);     // 25,600,000
  unsigned short* ell   = (unsigned short*)(ws + 140800000);     //  6,400,000 (u16, per-m reuse)
  float* el2            = (float*)(ws + 147200000);              //  3,200,000 [M][N][8]
  float* er2            = (float*)(ws + 150400000);              //  3,200,000 [M][N][8]
  int* deg2             = (int*)(ws + 153600000);                //    400,000 [2][N]
  unsigned short* WgbT  = (unsigned short*)(ws + 154000000);     //    524,288
  unsigned short* W1T   = (unsigned short*)(ws + 154524288);     //    131,072
  unsigned short* WoutT = (unsigned short*)(ws + 154655360);     //     65,536
  unsigned short* WALR  = (unsigned short*)(ws + 154720896);     //     16,384
  float* wsem           = (float*)(ws + 154737280);              //         64

  k_prep<<<1831, 256, 0, stream>>>(Wg, W1, Wout, al, ar, WgbT, W1T, WoutT, WALR,
                                   deg2, wsem);
  // fused: elx (782 blocks) + edge pass m=0 (3125 blocks)
  k_elx_edge<<<ELX_BLOCKS + 3125, 256, 0, stream>>>(x, WALR, xb, el2, er2,
                                                    src, dst, deg2, ell);

  for (int m = 0; m < M_PATHS; ++m) {
    dim3 gf(782, 2);
    k_gemm_feat<<<gf, 256, 0, stream>>>(xb, WgbT + (size_t)m * 131072, featb);
    k_agg<<<12500, 256, 0, stream>>>(featb, el2 + m * 400000, er2 + m * 400000,
                                     ell, deg2 + m * N_NODES, bg + m * HD, z);
    k_gemm_post<<<391, 256, 0, stream>>>(z, W1T, WoutT, b1, q, wsem + m,
                                         yb + (size_t)m * N_NODES * OUT_DIM);
    if (m == 0) {
      // edge pass for m=1 (ell buffer is free again after k_agg(m=0))
      k_edge_e<<<3125, 256, 0, stream>>>(src + E_EDGES, dst + E_EDGES,
                                         deg2 + N_NODES, ell);
    }
  }
  k_final<<<1563, 256, 0, stream>>>(yb, wsem, bout, out);
}